// Round 6
// baseline (502.837 us; speedup 1.0000x reference)
//
#include <hip/hip_runtime.h>
#include <hip/hip_bf16.h>

#define NROWS 131072
#define DIM   512
#define NK    64

typedef __attribute__((ext_vector_type(4))) float f32x4;
typedef __attribute__((ext_vector_type(8))) short s16x8;

// pack two fp32 -> one dword of two bf16 (RNE), low half = first arg
static __device__ __forceinline__ unsigned pk2(float a, float b) {
    union { __hip_bfloat162 h; unsigned u; } cv;
    cv.h = __float22bfloat162_rn(make_float2(a, b));
    return cv.u;
}

// --- Kernel 1: L2-normalize clusters (fp32) -> bf16 codebook in ws; zero loss slot.
__global__ void prep_kernel(const float* __restrict__ cl,
                            unsigned* __restrict__ cb,    // bf16[64][512] as dwords
                            float* __restrict__ loss_out) {
    const int k = blockIdx.x, t = threadIdx.x;
    const float4* rp = reinterpret_cast<const float4*>(cl + k * DIM);
    float4 f0 = rp[2 * t], f1 = rp[2 * t + 1];
    float ss = f0.x*f0.x + f0.y*f0.y + f0.z*f0.z + f0.w*f0.w
             + f1.x*f1.x + f1.y*f1.y + f1.z*f1.z + f1.w*f1.w;
#pragma unroll
    for (int m = 1; m < 64; m <<= 1) ss += __shfl_xor(ss, m, 64);
    const float rn = 1.0f / fmaxf(sqrtf(ss), 1e-12f);
    uint4 o;
    o.x = pk2(f0.x * rn, f0.y * rn);
    o.y = pk2(f0.z * rn, f0.w * rn);
    o.z = pk2(f1.x * rn, f1.y * rn);
    o.w = pk2(f1.z * rn, f1.w * rn);
    reinterpret_cast<uint4*>(cb + (size_t)k * (DIM / 2))[t] = o;
    if (k == 0 && t == 0) *loss_out = 0.0f;
}

// --- Kernel 2: fused normalize-x / MFMA GEMM / softmax / loss.
// v7 = v6 with ONE change: x prefetch pipeline depth 2 -> 4.
// History: v6 ((512,2) bound) eliminated the (512,4) 64-VGPR-clamp spill
// (231 -> ~156 us, writes back to ~ideal) but plateaued at v2's level.
// All spill-free configs pin at ~2.0 TB/s useful while SPILLING configs
// sustained 2.5 TB/s total -> the memory system has headroom; the limiter
// is per-wave outstanding bytes (MLP), not occupancy, not stores.
// Depth-4 doubles in-flight loads to ~8 KB/wave (v4 tried this but was
// killed by the 64-VGPR clamp; with the 256 budget the ~100-116 combined
// live set should land <=128 -> 16 waves/CU with the 74 KB LDS).
__global__ __launch_bounds__(512, 2) void fused_kernel(
        const float* __restrict__ x,
        const unsigned* __restrict__ cb,
        const float* __restrict__ alphap,
        float* __restrict__ out) {                 // [0]=loss, [1..]=probs[N][64]
    __shared__ unsigned short ldsb[NK * DIM];      // 64 KB codebook
    __shared__ float sbuf[8][4 * 80];              // 10 KB staging: 4 rows/wave, stride 80
                                                   //  (stride 80 -> <=2-way banks, free)

    // stage codebook: 4096 16B-units; unit c6 of row r stored at (c6 ^ (r&7))
    for (int u = threadIdx.x; u < NK * DIM / 8; u += blockDim.x) {
        const int r = u >> 6, c6 = u & 63;
        const uint4 v = reinterpret_cast<const uint4*>(cb)[u];
        *reinterpret_cast<uint4*>(&ldsb[r * DIM + ((c6 ^ (r & 7)) << 3)]) = v;
    }
    __syncthreads();

    const float alpha = alphap[0];
    const int lane = threadIdx.x & 63;
    const int n = lane & 15;            // A-row / B-col / C-col lane index
    const int q = lane >> 4;            // quad
    const int sw = n & 7;               // LDS unit swizzle for this lane's B rows
    float* sb = sbuf[threadIdx.x >> 6];
    const int gw = (int)((blockIdx.x * blockDim.x + threadIdx.x) >> 6);
    const int nw = (int)((gridDim.x * blockDim.x) >> 6);

    const unsigned short* b_base = &ldsb[n * DIM];

    float lossa = 0.0f;

    for (int g = gw; g < NROWS / 16; g += nw) {
        const int row0 = g << 4;
        const float4* xp4 = reinterpret_cast<const float4*>(
            x + (size_t)(row0 + n) * DIM + (q << 3));
        f32x4 a0 = {0.f,0.f,0.f,0.f}, a1 = {0.f,0.f,0.f,0.f};
        f32x4 a2 = {0.f,0.f,0.f,0.f}, a3 = {0.f,0.f,0.f,0.f};
        float ss = 0.0f;

        // 4-deep register pipeline on x; all indices compile-time after unroll
        float4 pf0[4], pf1[4];
#pragma unroll
        for (int j = 0; j < 4; j++) { pf0[j] = xp4[j * 8]; pf1[j] = xp4[j * 8 + 1]; }
#pragma unroll
        for (int t = 0; t < 16; t++) {
            const float4 c0 = pf0[t & 3], c1 = pf1[t & 3];
            if (t < 12) { pf0[t & 3] = xp4[(t + 4) * 8]; pf1[t & 3] = xp4[(t + 4) * 8 + 1]; }
            ss += c0.x*c0.x + c0.y*c0.y + c0.z*c0.z + c0.w*c0.w
                + c1.x*c1.x + c1.y*c1.y + c1.z*c1.z + c1.w*c1.w;
            union { s16x8 v; unsigned u[4]; } A;
            A.u[0] = pk2(c0.x, c0.y); A.u[1] = pk2(c0.z, c0.w);
            A.u[2] = pk2(c1.x, c1.y); A.u[3] = pk2(c1.z, c1.w);
            const int off = (((t << 2) | q) ^ sw) << 3;   // swizzled 16B unit
            const s16x8 b0 = *reinterpret_cast<const s16x8*>(b_base + off);
            const s16x8 b1 = *reinterpret_cast<const s16x8*>(b_base + 16 * DIM + off);
            const s16x8 b2 = *reinterpret_cast<const s16x8*>(b_base + 32 * DIM + off);
            const s16x8 b3 = *reinterpret_cast<const s16x8*>(b_base + 48 * DIM + off);
            a0 = __builtin_amdgcn_mfma_f32_16x16x32_bf16(A.v, b0, a0, 0, 0, 0);
            a1 = __builtin_amdgcn_mfma_f32_16x16x32_bf16(A.v, b1, a1, 0, 0, 0);
            a2 = __builtin_amdgcn_mfma_f32_16x16x32_bf16(A.v, b2, a2, 0, 0, 0);
            a3 = __builtin_amdgcn_mfma_f32_16x16x32_bf16(A.v, b3, a3, 0, 0, 0);
        }

        // finish ||x_row||: lanes (q,n) hold partials of row n
        ss += __shfl_xor(ss, 16, 64);
        ss += __shfl_xor(ss, 32, 64);
        const float rnorm = 1.0f / fmaxf(sqrtf(ss), 1e-12f);

        // carries: col 63 of rows {4q + r} from the previous r-iteration
        float carry0 = 0.f, carry1 = 0.f, carry2 = 0.f, carry3 = 0.f;

#pragma unroll
        for (int r = 0; r < 4; r++) {
            // C row = q*4 + r; its rnorm lives at lanes with (lane&15) == q*4+r
            const float rn = __shfl(rnorm, (q << 2) + r, 64);
            const float i0 = a0[r] * rn, i1 = a1[r] * rn, i2 = a2[r] * rn, i3 = a3[r] * rn;
            const float z0 = i0 * alpha, z1 = i1 * alpha, z2 = i2 * alpha, z3 = i3 * alpha;
            float mx = fmaxf(fmaxf(z0, z1), fmaxf(z2, z3));
#pragma unroll
            for (int m = 1; m < 16; m <<= 1) mx = fmaxf(mx, __shfl_xor(mx, m, 64));
            const float e0 = __expf(z0 - mx), e1 = __expf(z1 - mx);
            const float e2 = __expf(z2 - mx), e3 = __expf(z3 - mx);
            float s  = e0 + e1 + e2 + e3;
            float sl = e0 * i0 + e1 * i1 + e2 * i2 + e3 * i3;   // loss uses pre-alpha ip
#pragma unroll
            for (int m = 1; m < 16; m <<= 1) {
                s  += __shfl_xor(s,  m, 64);
                sl += __shfl_xor(sl, m, 64);
            }
            const float inv = 1.0f / s;
            const float p0 = e0 * inv, p1 = e1 * inv, p2 = e2 * inv, p3 = e3 * inv;
            if (n == 0) lossa += sl * inv;      // one contribution per row

            // stage this iteration's 4 rows (row 4q+r into slot q)
            float* sq = sb + q * 80;
            sq[n]      = p0;
            sq[n + 16] = p1;
            sq[n + 32] = p2;
            sq[n + 48] = p3;

            // 4 aligned 256-B shifted-window stores: row k=4*qq+r,
            // out[(row0+k)*64+lane] = tile elem k*64+lane-1
#pragma unroll
            for (int qq = 0; qq < 4; qq++) {
                const float lv = sb[qq * 80 + (lane ? lane - 1 : 0)];
                const float cq = qq == 0 ? carry0 : qq == 1 ? carry1
                                : qq == 2 ? carry2 : carry3;
                const float v = lane ? lv : cq;
                if (r == 0) {
                    if (lane > 0)       // lane0: qq==0 from prev group; qq>0 patched
                        out[(size_t)(row0 + (qq << 2)) * 64 + lane] = v;
                } else {
                    out[(size_t)(row0 + (qq << 2) + r) * 64 + lane] = v;
                }
            }
            // update carries to this iteration's col-63 values (rows 4q+r)
            carry0 = __shfl(p3, 15, 64);
            carry1 = __shfl(p3, 31, 64);
            carry2 = __shfl(p3, 47, 64);
            carry3 = __shfl(p3, 63, 64);
        }

        // patches: after r=3, carries hold col63 of rows 3,7,11,15.
        // They are exactly the masked lane-0 dwords of rows 4,8,12 plus the
        // next group's first aligned slot (elem 1023 convention from v2).
        if (lane == 0) {
            out[(size_t)(row0 + 4)  * 64] = carry0;
            out[(size_t)(row0 + 8)  * 64] = carry1;
            out[(size_t)(row0 + 12) * 64] = carry2;
            out[(size_t)(row0 + 16) * 64] = carry3;
        }
    }

    // wave-level loss partials live in lanes 0,16,32,48
    lossa += __shfl_xor(lossa, 16, 64);
    lossa += __shfl_xor(lossa, 32, 64);
    if (lane == 0) atomicAdd(out, -lossa * (1.0f / NROWS));
}

extern "C" void kernel_launch(void* const* d_in, const int* in_sizes, int n_in,
                              void* d_out, int out_size, void* d_ws, size_t ws_size,
                              hipStream_t stream) {
    const float* x  = (const float*)d_in[0];
    const float* cl = (const float*)d_in[1];
    const float* al = (const float*)d_in[2];
    float* out = (float*)d_out;
    unsigned* cb = (unsigned*)d_ws;            // 64 KB bf16 codebook

    prep_kernel<<<dim3(NK), dim3(64), 0, stream>>>(cl, cb, out);
    fused_kernel<<<dim3(512), dim3(512), 0, stream>>>(x, cb, al, out);
}

// Round 7
// 406.813 us; speedup vs baseline: 1.2360x; 1.2360x over previous
//
#include <hip/hip_runtime.h>
#include <hip/hip_bf16.h>

#define NROWS 131072
#define DIM   512
#define NK    64
#define GPB   16   // 16-row groups per block: 8192 groups / 512 blocks

typedef __attribute__((ext_vector_type(4))) float f32x4;
typedef __attribute__((ext_vector_type(8))) short s16x8;

// pack two fp32 -> one dword of two bf16 (RNE), low half = first arg
static __device__ __forceinline__ unsigned pk2(float a, float b) {
    union { __hip_bfloat162 h; unsigned u; } cv;
    cv.h = __float22bfloat162_rn(make_float2(a, b));
    return cv.u;
}

// Barrier that does NOT drain vmcnt (prefetch loads stay in flight across it).
// LDS ordering via lgkmcnt(0); asm memory clobbers bracket the raw s_barrier
// so the compiler cannot move LDS ops across the region.
static __device__ __forceinline__ void lds_barrier() {
    asm volatile("s_waitcnt lgkmcnt(0)" ::: "memory");
    __builtin_amdgcn_s_barrier();
    asm volatile("" ::: "memory");
}

// --- Kernel 1: L2-normalize clusters (fp32) -> bf16 codebook in ws; zero loss slot.
__global__ void prep_kernel(const float* __restrict__ cl,
                            unsigned* __restrict__ cb,    // bf16[64][512] as dwords
                            float* __restrict__ loss_out) {
    const int k = blockIdx.x, t = threadIdx.x;
    const float4* rp = reinterpret_cast<const float4*>(cl + k * DIM);
    float4 f0 = rp[2 * t], f1 = rp[2 * t + 1];
    float ss = f0.x*f0.x + f0.y*f0.y + f0.z*f0.z + f0.w*f0.w
             + f1.x*f1.x + f1.y*f1.y + f1.z*f1.z + f1.w*f1.w;
#pragma unroll
    for (int m = 1; m < 64; m <<= 1) ss += __shfl_xor(ss, m, 64);
    const float rn = 1.0f / fmaxf(sqrtf(ss), 1e-12f);
    uint4 o;
    o.x = pk2(f0.x * rn, f0.y * rn);
    o.y = pk2(f0.z * rn, f0.w * rn);
    o.z = pk2(f1.x * rn, f1.y * rn);
    o.w = pk2(f1.z * rn, f1.w * rn);
    reinterpret_cast<uint4*>(cb + (size_t)k * (DIM / 2))[t] = o;
    if (k == 0 && t == 0) *loss_out = 0.0f;
}

// --- Kernel 2 (v8): block-cooperative K-split.
// Theory: v2/v6 pinned at ~2.0 TB/s useful with ALL pipes idle. Chip-wide the
// old layout had 65536 concurrent stride-2KB row-streams advancing 128B/iter
// -> DRAM page thrash (fill kernel does 6.6 TB/s on the same chip).
// Now the 8 waves of a block share ONE 16-row group; wave w owns k-blocks
// t=2w,2w+1 (k floats [w*64,w*64+64)). Each x row is consumed as a burst of
// 16 near-simultaneous 128B requests; concurrent streams drop 8x.
// Structural wins: B-fragments are per-wave constants -> codebook lives in
// 32 VGPRs loaded once; no LDS codebook, no staging loop, no atomics
// (per-wave partial strips + tree sum in epilogue), no zeroing.
// lgkm-only barriers keep the 1-group-ahead register prefetch in flight.
__global__ __launch_bounds__(512, 2) void fused_kernel(
        const float* __restrict__ x,
        const unsigned* __restrict__ cb,
        const float* __restrict__ alphap,
        float* __restrict__ out) {                 // [0]=loss, [1..]=probs[N][64]
    __shared__ float part[8][16][65];   // per-wave C partials; part[0] doubles as p-tile
    __shared__ float ssp[8][16];        // per-wave ||row||^2 partials

    const int tid  = threadIdx.x;
    const int lane = tid & 63, wid = tid >> 6;
    const int n = lane & 15, q = lane >> 4;

    // One-time B-fragments for this wave's two k-blocks (32 VGPRs).
    // 16B unit (cluster, t, q) = cluster*64 + 4*t + q; t = 2*wid + tt.
    const s16x8* cbv = reinterpret_cast<const s16x8*>(cb);
    const int tb = (wid << 3) + q;      // 8*wid + q
    const s16x8 bf00 = cbv[(n)      * 64 + tb],     bf01 = cbv[(n)      * 64 + tb + 4];
    const s16x8 bf10 = cbv[(n + 16) * 64 + tb],     bf11 = cbv[(n + 16) * 64 + tb + 4];
    const s16x8 bf20 = cbv[(n + 32) * 64 + tb],     bf21 = cbv[(n + 32) * 64 + tb + 4];
    const s16x8 bf30 = cbv[(n + 48) * 64 + tb],     bf31 = cbv[(n + 48) * 64 + tb + 4];

    const float alpha = alphap[0];
    const int g0 = (int)blockIdx.x * GPB;
    const size_t lrow = (size_t)n * DIM + (wid << 6) + (q << 3);  // lane's offset in a group

    float lossa = 0.0f;

    auto process = [&](int gi, const float4& c0, const float4& c1,
                       const float4& d0, const float4& d1) {
        const int row0 = (g0 + gi) << 4;
        // row-norm partial over this wave's 16 k-floats (fp32, pre-bf16)
        float ss = c0.x*c0.x + c0.y*c0.y + c0.z*c0.z + c0.w*c0.w
                 + c1.x*c1.x + c1.y*c1.y + c1.z*c1.z + c1.w*c1.w
                 + d0.x*d0.x + d0.y*d0.y + d0.z*d0.z + d0.w*d0.w
                 + d1.x*d1.x + d1.y*d1.y + d1.z*d1.z + d1.w*d1.w;
        ss += __shfl_xor(ss, 16, 64);
        ss += __shfl_xor(ss, 32, 64);
        if (lane < 16) ssp[wid][lane] = ss;     // lanes n,n+16,.. hold row-n sum

        // MFMA: 2 k-iters x 4 col-blocks, partial C for this wave's k-slice
        f32x4 a0 = {0.f,0.f,0.f,0.f}, a1 = a0, a2 = a0, a3 = a0;
        union { s16x8 v; unsigned u[4]; } A;
        A.u[0] = pk2(c0.x, c0.y); A.u[1] = pk2(c0.z, c0.w);
        A.u[2] = pk2(c1.x, c1.y); A.u[3] = pk2(c1.z, c1.w);
        a0 = __builtin_amdgcn_mfma_f32_16x16x32_bf16(A.v, bf00, a0, 0, 0, 0);
        a1 = __builtin_amdgcn_mfma_f32_16x16x32_bf16(A.v, bf10, a1, 0, 0, 0);
        a2 = __builtin_amdgcn_mfma_f32_16x16x32_bf16(A.v, bf20, a2, 0, 0, 0);
        a3 = __builtin_amdgcn_mfma_f32_16x16x32_bf16(A.v, bf30, a3, 0, 0, 0);
        A.u[0] = pk2(d0.x, d0.y); A.u[1] = pk2(d0.z, d0.w);
        A.u[2] = pk2(d1.x, d1.y); A.u[3] = pk2(d1.z, d1.w);
        a0 = __builtin_amdgcn_mfma_f32_16x16x32_bf16(A.v, bf01, a0, 0, 0, 0);
        a1 = __builtin_amdgcn_mfma_f32_16x16x32_bf16(A.v, bf11, a1, 0, 0, 0);
        a2 = __builtin_amdgcn_mfma_f32_16x16x32_bf16(A.v, bf21, a2, 0, 0, 0);
        a3 = __builtin_amdgcn_mfma_f32_16x16x32_bf16(A.v, bf31, a3, 0, 0, 0);

        // write partial tile (plain stores; <=4-way bank alias, no atomics)
#pragma unroll
        for (int rr = 0; rr < 4; rr++) {
            const int cr = (q << 2) + rr;      // x-row within group
            part[wid][cr][n]      = a0[rr];
            part[wid][cr][n + 16] = a1[rr];
            part[wid][cr][n + 32] = a2[rr];
            part[wid][cr][n + 48] = a3[rr];
        }
        lds_barrier();  // B1: all partials + ss visible

        // epilogue: wave owns x-rows 2*wid, 2*wid+1; 64-lane row softmax
#pragma unroll
        for (int e = 0; e < 2; e++) {
            const int k = (wid << 1) + e;
            const float sv = ssp[0][k] + ssp[1][k] + ssp[2][k] + ssp[3][k]
                           + ssp[4][k] + ssp[5][k] + ssp[6][k] + ssp[7][k];
            const float c  = part[0][k][lane] + part[1][k][lane] + part[2][k][lane]
                           + part[3][k][lane] + part[4][k][lane] + part[5][k][lane]
                           + part[6][k][lane] + part[7][k][lane];
            const float rn = 1.0f / fmaxf(sqrtf(sv), 1e-12f);
            const float ip = c * rn;
            const float z  = ip * alpha;
            float mx = z;
#pragma unroll
            for (int m = 1; m < 64; m <<= 1) mx = fmaxf(mx, __shfl_xor(mx, m, 64));
            const float ev = __expf(z - mx);
            float s = ev, sl = ev * ip;          // loss uses pre-alpha ip
#pragma unroll
            for (int m = 1; m < 64; m <<= 1) {
                s  += __shfl_xor(s,  m, 64);
                sl += __shfl_xor(sl, m, 64);
            }
            const float inv = 1.0f / s;
            part[0][k][lane] = ev * inv;         // p-tile writeback (own row only)
            if (lane == 0) lossa += sl * inv;    // one contribution per row
        }
        lds_barrier();  // B2: p-tile complete

        // 256-B-aligned shifted-window stores: out[(row0+k)*64+lane] = p-flat[k*64+lane-1]
        const float* cf = &part[0][0][0];
#pragma unroll
        for (int e = 0; e < 2; e++) {
            const int k = (wid << 1) + e;
            if (k > 0 || lane > 0) {
                const int ei = (k << 6) + lane - 1;
                out[(size_t)(row0 + k) * 64 + lane] = cf[(ei >> 6) * 65 + (ei & 63)];
            }
        }
        if (tid == 0) out[(size_t)(row0 + 16) * 64] = cf[15 * 65 + 63];  // elem 1023
        lds_barrier();  // B3: stores done reading p-tile before next group's writes
    };

    // register prefetch, one group ahead (survives lgkm-only barriers)
    float4 Aa, Ab, Ac, Ad, Ba, Bb, Bc, Bd;
    {
        const float4* p = reinterpret_cast<const float4*>(x + (size_t)(g0 << 4) * DIM + lrow);
        Aa = p[0]; Ab = p[1]; Ac = p[8]; Ad = p[9];
    }
    for (int gi = 0; gi < GPB; gi += 2) {
        {   const float4* p = reinterpret_cast<const float4*>(
                x + (size_t)((g0 + gi + 1) << 4) * DIM + lrow);
            Ba = p[0]; Bb = p[1]; Bc = p[8]; Bd = p[9]; }
        process(gi, Aa, Ab, Ac, Ad);
        if (gi + 2 < GPB) {
            const float4* p = reinterpret_cast<const float4*>(
                x + (size_t)((g0 + gi + 2) << 4) * DIM + lrow);
            Aa = p[0]; Ab = p[1]; Ac = p[8]; Ad = p[9];
        }
        process(gi + 1, Ba, Bb, Bc, Bd);
    }

    if (lane == 0) atomicAdd(out, -lossa * (1.0f / NROWS));
}

extern "C" void kernel_launch(void* const* d_in, const int* in_sizes, int n_in,
                              void* d_out, int out_size, void* d_ws, size_t ws_size,
                              hipStream_t stream) {
    const float* x  = (const float*)d_in[0];
    const float* cl = (const float*)d_in[1];
    const float* al = (const float*)d_in[2];
    float* out = (float*)d_out;
    unsigned* cb = (unsigned*)d_ws;            // 64 KB bf16 codebook

    prep_kernel<<<dim3(NK), dim3(64), 0, stream>>>(cl, cb, out);
    fused_kernel<<<dim3(NROWS / 16 / GPB), dim3(512), 0, stream>>>(x, cb, al, out);
}